// Round 9
// baseline (2187.951 us; speedup 1.0000x reference)
//
#include <hip/hip_runtime.h>
#include <hip/hip_bf16.h>
#include <cstdint>

using bf16 = __hip_bfloat16;
typedef __attribute__((ext_vector_type(8))) short bf16x8;
typedef __attribute__((ext_vector_type(4))) float f32x4;

struct alignas(16) B8 { bf16 h[8]; };
struct alignas(8)  B4 { bf16 h[4]; };

__device__ __forceinline__ void gll16(const void* g, void* l) {
  __builtin_amdgcn_global_load_lds((__attribute__((address_space(1))) void*)g,
                                   (__attribute__((address_space(3))) void*)l,
                                   16, 0, 0);
}

// =================================================================================
// FRAGMENT-MAJOR GLOBAL LAYOUT: for a [rows][1024] operand, 16-B chunk id =
//   ((row>>4)*128 + (k>>3))*16 + (row&15)      (chunk content = 8 bf16 k-elems)
// Staging a 16-row group x 32-k section = 64 CONSECUTIVE chunks -> each gll16
// reads 1KB fully contiguous (perfect coalescing) and lands linearly in LDS in
// exactly fragment order -> frag ds_read_b128 = base + lane*16 (zero conflicts).
// =================================================================================

// ---------------- x fp32 [32768][1024] -> fragment-major bf16 ----------------
__global__ __launch_bounds__(256) void cast_x_frag(const float* __restrict__ x,
                                                   bf16* __restrict__ xr) {
  __shared__ float tile[16][257];
  const int g = blockIdx.x;                    // 16-row group, 0..2047
  const int t = threadIdx.x;
  const float* src = x + (size_t)g * 16384;    // 16 rows * 1024
  bf16* dst = xr + (size_t)g * 16384;          // 2048 chunks * 8 elems
  for (int kp = 0; kp < 4; ++kp) {
    const int k0 = kp * 256;
    if (kp) __syncthreads();
    {
      const int r = t >> 4, cl = t & 15;       // lanes 0..15 read 64B contiguous
      #pragma unroll
      for (int s = 0; s < 16; ++s)
        tile[r][cl + 16 * s] = src[(size_t)r * 1024 + k0 + cl + 16 * s];
    }
    __syncthreads();
    #pragma unroll
    for (int rd = 0; rd < 2; ++rd) {
      const int c = rd * 256 + t;
      const int ql = c >> 4, r = c & 15;       // bank = r + 8q + jj: conflict-free
      B8 o;
      #pragma unroll
      for (int jj = 0; jj < 8; ++jj) o.h[jj] = __float2bfloat16(tile[r][ql * 8 + jj]);
      *(B8*)(dst + ((size_t)(kp * 32 + ql) * 16 + r) * 8) = o;   // contiguous stores
    }
  }
}

// ---------------- W fp32 [K][N] -> fragment-major bf16 of W^T ----------------
// out chunk = (((n_glob0+n)>>4)*128 + (k>>3))*16 + (n&15)
__global__ __launch_bounds__(256) void wcast_frag(const float* __restrict__ W,
                                                  bf16* __restrict__ out,
                                                  int N, int n_glob0) {
  __shared__ float tw[256][17];
  const int k0 = blockIdx.x * 256;
  const int n0 = blockIdx.y * 16;
  const int t = threadIdx.x;
  {
    const int nn = t & 15, kk0 = t >> 4;       // lanes 0..15: 64B contiguous per row
    #pragma unroll
    for (int s = 0; s < 16; ++s) {
      const int kk = kk0 + 16 * s;
      tw[kk][nn] = W[(size_t)(k0 + kk) * N + n0 + nn];
    }
  }
  __syncthreads();
  const int ng = (n_glob0 + n0) >> 4;
  #pragma unroll
  for (int rd = 0; rd < 2; ++rd) {
    const int c = rd * 256 + t;
    const int ql = c >> 4, r = c & 15;         // bank = 8q + 17jj + r: free
    B8 o;
    #pragma unroll
    for (int jj = 0; jj < 8; ++jj) o.h[jj] = __float2bfloat16(tw[ql * 8 + jj][r]);
    *(B8*)(out + (((size_t)ng * 128 + (k0 >> 3) + ql) * 16 + r) * 8) = o;
  }
}

// ---------------- transpose + cast: W[K][N] fp32 -> WT[N][K] bf16 (row-major) ----
__global__ void tcast(const float* __restrict__ W, bf16* __restrict__ WT, int K, int N) {
  __shared__ float tile[32][33];
  int k0 = blockIdx.y * 32, n0 = blockIdx.x * 32;
  int tx = threadIdx.x, ty = threadIdx.y;  // block (32,8)
  for (int yy = ty; yy < 32; yy += 8)
    tile[yy][tx] = W[(size_t)(k0 + yy) * N + n0 + tx];
  __syncthreads();
  for (int yy = ty; yy < 32; yy += 8)
    WT[(size_t)(n0 + yy) * K + k0 + tx] = __float2bfloat16(tile[tx][yy]);
}

// =================================================================================
// Shared 256x256-tile, BK=32-per-section, 8-wave main loop (K=1024, 32 sections).
// NEW (r9): 2-SLOT RING, 64 KB LDS -> 2 BLOCKS/CU. The per-section structure is
// the guide's minimum 2-phase: STAGE(s^1) -> ds_read(s) -> lgkm(0) -> MFMA x32
// (a2 reads interleaved in cluster 1) -> vmcnt(0) + barrier. The vmcnt(0) drain
// stalls this block, but the CO-RESIDENT second block fills the gap (m114: MFMA
// and memory pipes of different waves overlap, time ~ max not sum). Per-CU MFMA
// aggregate for a section-pair = 2x1242 cyc ~ the old 1-block section time.
// WAR audit: all reads of slot s drain at the wave's own lgkm(0)s before its
// barrier-arrival; stage of s^1 issues only after that barrier; stage lands via
// the end-of-section vmcnt(0)+barrier. No cross-section ds_read prefetch -> no
// read/DMA races. Fragment-major global operands (r7): staging coalesced 1KB
// per gll16, frag reads conflict-free.
// =================================================================================
__device__ __forceinline__ void gemm_mainloop_256(
    const bf16* __restrict__ aop0, const bf16* __restrict__ aop1,
    const bf16* __restrict__ bop0, const bf16* __restrict__ bop1,
    bf16* ldsA, bf16* ldsB, int wd0, int wd1,
    int aoff, int boff, f32x4 (&acc)[8][4])
{
#define STAGE_A(slot, ko) do { gll16(aop0 + (ko) * 16, ldsA + (slot) * 8192 + wd0); \
                               gll16(aop1 + (ko) * 16, ldsA + (slot) * 8192 + wd1); } while (0)
#define STAGE_B(slot, ko) do { gll16(bop0 + (ko) * 16, ldsB + (slot) * 8192 + wd0); \
                               gll16(bop1 + (ko) * 16, ldsB + (slot) * 8192 + wd1); } while (0)
#define AFRAG(slot, i) (*(const bf16x8*)(ldsA + (slot) * 8192 + aoff + (i) * 512))
#define BFRAG(slot, j) (*(const bf16x8*)(ldsB + (slot) * 8192 + boff + (j) * 512))

  bf16x8 a1[4], a2[4], bb[4];

  // prologue: stage slot 0, drain, sync
  STAGE_A(0, 0); STAGE_B(0, 0);
  asm volatile("s_waitcnt vmcnt(0)" ::: "memory");
  __builtin_amdgcn_s_barrier();
  __builtin_amdgcn_sched_barrier(0);

  #pragma unroll 2
  for (int v = 0; v < 32; ++v) {
    const int s = v & 1;
    if (v < 31) { STAGE_A(s ^ 1, (v + 1) * 32); STAGE_B(s ^ 1, (v + 1) * 32); }
    #pragma unroll
    for (int j = 0; j < 4; j++) bb[j] = BFRAG(s, j);
    #pragma unroll
    for (int i = 0; i < 4; i++) a1[i] = AFRAG(s, i);
    asm volatile("s_waitcnt lgkmcnt(0)" ::: "memory");
    __builtin_amdgcn_sched_barrier(0);
    __builtin_amdgcn_s_setprio(1);
    #pragma unroll
    for (int i = 0; i < 4; i++) {
      #pragma unroll
      for (int j = 0; j < 4; j++)
        acc[i][j] = __builtin_amdgcn_mfma_f32_16x16x32_bf16(a1[i], bb[j], acc[i][j], 0, 0, 0);
      a2[i] = AFRAG(s, i + 4);
    }
    asm volatile("s_waitcnt lgkmcnt(0)" ::: "memory");
    __builtin_amdgcn_sched_barrier(0);
    #pragma unroll
    for (int i = 0; i < 4; i++)
      #pragma unroll
      for (int j = 0; j < 4; j++)
        acc[i + 4][j] = __builtin_amdgcn_mfma_f32_16x16x32_bf16(a2[i], bb[j], acc[i + 4][j], 0, 0, 0);
    __builtin_amdgcn_s_setprio(0);
    asm volatile("s_waitcnt vmcnt(0)" ::: "memory");
    __builtin_amdgcn_s_barrier();
    __builtin_amdgcn_sched_barrier(0);
  }
#undef STAGE_A
#undef STAGE_B
#undef AFRAG
#undef BFRAG
}

// =================================================================================
// Fused QKV GEMM:  T = x_bf @ [Wq | Wkv]  (M=32768, N=3072, K=1024)
//  - all operands fragment-major; XCD-chunked swizzle 1536 = 8 x 192 (bm-major).
//  - q tiles (bn<4): per-row softmax over the wave's 64-col head slice (* DH^-0.5);
//    Yq written FRAGMENT-MAJOR (consumed by gemm_out staging).
//  - kv tiles: 2 heads/block, processed ONE AT A TIME in 64 KB LDS (2 passes):
//    pass hp: the 4 waves holding head hp write exp(k)/v (swizzled [64][256]);
//    sync; all 8 waves compute R[d][e] partials (wave = (ks-half, d-quad)), fp32
//    atomics merge. Z stays register-resident (shfl reduce), atomics at end.
// =================================================================================
constexpr int QKV_NT = 12;   // N/256

__global__ __launch_bounds__(512, 4)
void gemm_qkv(const bf16* __restrict__ A, const bf16* __restrict__ BT,
              bf16* __restrict__ Yq, float* __restrict__ ctxAcc)
{
  __shared__ __align__(16) union {
    struct { bf16 a[2 * 8192]; bf16 b[2 * 8192]; } g;   // 2+2 slots (16KB each) = 64KB
    struct { bf16 ekT[16384]; bf16 vT[16384]; } c;      // kv epilogue, ONE head = 64KB
  } sm;

  const int t = threadIdx.x;
  const int wave = t >> 6, lane = t & 63;
  const int lr = lane & 15, kq = lane >> 4;
  const int wm = wave >> 2, wn = wave & 3;
  // XCD-chunked swizzle (bijective: 1536 = 8 * 192; dispatch round-robins bid%8)
  const int bid = (int)blockIdx.x;
  const int swz = (bid & 7) * 192 + (bid >> 3);
  const int bm = swz / QKV_NT, bn = swz % QKV_NT;
  const int m0 = bm * 256, n0 = bn * 256;

  // ---- staging pointers: wave stages 16-row group (m0>>4)+wave (+8 for aop1);
  //      lane sources chunk base + lane (1KB contiguous per gll16).
  const bf16* aop0 = A + (size_t)((m0 >> 4) + wave) * 16384 + lane * 8;
  const bf16* aop1 = aop0 + 131072;
  const bf16* bop0 = BT + (size_t)((n0 >> 4) + wave) * 16384 + lane * 8;
  const bf16* bop1 = bop0 + 131072;
  const int wd0 = wave * 512;          // elems, wave-uniform dest (gll writes base+lane*16)
  const int wd1 = 4096 + wave * 512;

  // ---- fragment-read offsets (contiguous 1KB per frag; lane*8 elems within)
  const int aoff = wm * 4096 + lane * 8;   // + i*512 per i-tile
  const int boff = wn * 2048 + lane * 8;   // + j*512 per j-tile

  const f32x4 zero = {0.f, 0.f, 0.f, 0.f};
  f32x4 acc[8][4];
  #pragma unroll
  for (int i = 0; i < 8; i++)
    #pragma unroll
    for (int j = 0; j < 4; j++) acc[i][j] = zero;

  gemm_mainloop_256(aop0, aop1, bop0, bop1, sm.g.a, sm.g.b, wd0, wd1,
                    aoff, boff, acc);

  if (bn < 4) {
    // ---- fused q softmax; Yq written fragment-major ----
    const int qb = (n0 + wn * 64) >> 3;
    const int jo = (lr >> 3) * 128;
    #pragma unroll
    for (int i = 0; i < 8; i++) {
      #pragma unroll
      for (int r = 0; r < 4; r++) {
        float m = fmaxf(fmaxf(acc[i][0][r], acc[i][1][r]),
                        fmaxf(acc[i][2][r], acc[i][3][r]));
        m = fmaxf(m, __shfl_xor(m, 1));
        m = fmaxf(m, __shfl_xor(m, 2));
        m = fmaxf(m, __shfl_xor(m, 4));
        m = fmaxf(m, __shfl_xor(m, 8));
        float ex[4]; float s = 0.f;
        #pragma unroll
        for (int j = 0; j < 4; j++) { ex[j] = __expf(acc[i][j][r] - m); s += ex[j]; }
        s += __shfl_xor(s, 1);
        s += __shfl_xor(s, 2);
        s += __shfl_xor(s, 4);
        s += __shfl_xor(s, 8);
        const float inv = 0.125f / s;           // scale = DH^-0.5
        const int row = m0 + wm * 128 + i * 16 + kq * 4 + r;
        bf16* yb = Yq + (((size_t)(row >> 4) * 128 + qb) * 16 + (row & 15)) * 8 + (lr & 7);
        #pragma unroll
        for (int j = 0; j < 4; j++)
          yb[j * 256 + jo] = __float2bfloat16(ex[j] * inv);
      }
    }
  } else {
    // ---- fused context: 256 s-rows x 2 heads, one head per pass (64 KB LDS) ----
    const int bb2 = m0 >> 12;                 // batch (4096 rows per batch)
    const int h0 = (n0 - 1024) >> 7;          // first head of this tile
    const int hloc = wn >> 1, isV = wn & 1;   // which head/operand this wave holds

    float zp[4] = {0.f, 0.f, 0.f, 0.f};
    #pragma unroll
    for (int hp = 0; hp < 2; ++hp) {
      if (hp) __syncthreads();                // pass-0 R reads done before overwrite
      if (hloc == hp) {
        bf16* const dstT = isV ? sm.c.vT : sm.c.ekT;
        #pragma unroll
        for (int i = 0; i < 8; i++) {
          const int sbase = wm * 128 + i * 16 + kq * 4;
          const int sxo = sbase >> 3;         // chunk (constant across r)
          const int sby = (sbase & 7) * 2;    // byte offset within chunk (0 or 8)
          #pragma unroll
          for (int j = 0; j < 4; j++) {
            const int d = j * 16 + lr;
            B4 pk;
            if (!isV) {
              #pragma unroll
              for (int r = 0; r < 4; r++) {
                float e = __expf(acc[i][j][r]);
                zp[j] += e;
                pk.h[r] = __float2bfloat16(e);
              }
            } else {
              #pragma unroll
              for (int r = 0; r < 4; r++) pk.h[r] = __float2bfloat16(acc[i][j][r]);
            }
            *(B4*)((char*)dstT + d * 512 + ((sxo ^ (d & 7)) << 4) + sby) = pk;
          }
        }
      }
      __syncthreads();

      // R[d][e] partial via MFMA for head h0+hp: wave -> (ks-half = wave>>2,
      // d-quad = wave&3); the two ks-halves' partials merge via the atomics.
      const int dq = wave & 3, ksh = wave >> 2;
      f32x4 racc[4] = {zero, zero, zero, zero};
      #pragma unroll
      for (int ks = 0; ks < 4; ks++) {
        const int ch = (ksh * 4 + ks) * 4 + kq;
        bf16x8 af = *(const bf16x8*)((const char*)sm.c.ekT + (dq * 16 + lr) * 512 + ((ch ^ (lr & 7)) << 4));
        #pragma unroll
        for (int j = 0; j < 4; j++) {
          bf16x8 bfr = *(const bf16x8*)((const char*)sm.c.vT + (j * 16 + lr) * 512 + ((ch ^ (lr & 7)) << 4));
          racc[j] = __builtin_amdgcn_mfma_f32_16x16x32_bf16(af, bfr, racc[j], 0, 0, 0);
        }
      }
      float* cb = ctxAcc + (size_t)(bb2 * 16 + h0 + hp) * 4160;
      #pragma unroll
      for (int j = 0; j < 4; j++) {
        #pragma unroll
        for (int r = 0; r < 4; r++)
          atomicAdd(cb + (dq * 16 + kq * 4 + r) * 64 + j * 16 + lr, racc[j][r]);
      }
    }

    if (!isV) {
      // Z[d] partial over this wave's 128 s-rows, straight from registers
      #pragma unroll
      for (int j = 0; j < 4; j++) {
        zp[j] += __shfl_xor(zp[j], 16);
        zp[j] += __shfl_xor(zp[j], 32);
      }
      if (kq == 0) {
        float* zb = ctxAcc + (size_t)(bb2 * 16 + h0 + hloc) * 4160 + 4096;
        #pragma unroll
        for (int j = 0; j < 4; j++) atomicAdd(zb + j * 16 + lr, zp[j]);
      }
    }
  }
}

// ---------------- W2T[b] = (R/Z) @ WlinT-slice, written FRAGMENT-MAJOR ----------
__global__ __launch_bounds__(256) void make_w2t(const float* __restrict__ ctxAcc,
                                                const bf16* __restrict__ WlinT,
                                                bf16* __restrict__ W2T) {
  const int nc = blockIdx.x;      // 0..15
  const int bh = blockIdx.y;      // 0..127
  const int b = bh >> 4, h = bh & 15;
  const int t = threadIdx.x, lane = t & 63, w = t >> 6;
  const float* src = ctxAcc + (size_t)bh * 4160;
  const float invz = 1.0f / src[4096 + lane];   // Z[d], d = lane
  float creg[64];
  const float* crow = src + lane * 64;
  #pragma unroll
  for (int e4 = 0; e4 < 16; e4++) {
    float4 v = *(const float4*)(crow + e4 * 4);
    creg[e4 * 4 + 0] = v.x * invz; creg[e4 * 4 + 1] = v.y * invz;
    creg[e4 * 4 + 2] = v.z * invz; creg[e4 * 4 + 3] = v.w * invz;
  }
  for (int i = 0; i < 16; i++) {
    const int n = nc * 64 + w * 16 + i;
    const bf16* wrow = WlinT + (size_t)n * 1024 + h * 64;
    float acc = 0.f;
    #pragma unroll
    for (int e8 = 0; e8 < 8; e8++) {
      B8 v = *(const B8*)(wrow + e8 * 8);
      #pragma unroll
      for (int j = 0; j < 8; j++) acc += creg[e8 * 8 + j] * __bfloat162float(v.h[j]);
    }
    // fragment-major: col = h*64+lane -> q = h*8 + (lane>>3), e = lane&7
    W2T[(size_t)b * 1048576 +
        (((size_t)(n >> 4) * 128 + h * 8 + (lane >> 3)) * 16 + (n & 15)) * 8 + (lane & 7)]
        = __float2bfloat16(acc);
  }
}

// ---------------- out[b] = Yq[b] @ W2T[b]^T + blin, fp32 output -------------------
// per batch: M=4096, N=1024, K=1024; fragment-major operands; grid 512 (2 blocks/CU)
// XCD-chunked swizzle: each XCD owns one batch (64 blocks): W2T[b] (2MB) L2-resident.
__global__ __launch_bounds__(512, 4)
void gemm_out(const bf16* __restrict__ Aall, const bf16* __restrict__ BTall,
              float* __restrict__ Call, const float* __restrict__ bias)
{
  __shared__ __align__(16) struct { bf16 a[2 * 8192]; bf16 b[2 * 8192]; } sm;
  const int t = threadIdx.x;
  const int wave = t >> 6, lane = t & 63;
  const int lr = lane & 15, kq = lane >> 4;
  const int wm = wave >> 2, wn = wave & 3;
  // bijective XCD swizzle: 512 = 8 * 64; XCD x -> batch x
  const int bid = (int)blockIdx.x;
  const int swz = (bid & 7) * 64 + (bid >> 3);
  const int bz = swz >> 6;
  const int r  = swz & 63;
  const int bm = r >> 2, bn = r & 3;
  const int m0 = bm * 256, n0 = bn * 256;
  const bf16* A  = Aall  + (size_t)bz * 4194304;
  const bf16* BT = BTall + (size_t)bz * 1048576;
  float* C       = Call  + (size_t)bz * 4194304;

  const bf16* aop0 = A + (size_t)((m0 >> 4) + wave) * 16384 + lane * 8;
  const bf16* aop1 = aop0 + 131072;
  const bf16* bop0 = BT + (size_t)((n0 >> 4) + wave) * 16384 + lane * 8;
  const bf16* bop1 = bop0 + 131072;
  const int wd0 = wave * 512;
  const int wd1 = 4096 + wave * 512;

  const int aoff = wm * 4096 + lane * 8;
  const int boff = wn * 2048 + lane * 8;

  const f32x4 zero = {0.f, 0.f, 0.f, 0.f};
  f32x4 acc[8][4];
  #pragma unroll
  for (int i = 0; i < 8; i++)
    #pragma unroll
    for (int j = 0; j < 4; j++) acc[i][j] = zero;

  gemm_mainloop_256(aop0, aop1, bop0, bop1, sm.a, sm.b, wd0, wd1,
                    aoff, boff, acc);

  float bv[4];
  #pragma unroll
  for (int j = 0; j < 4; j++) bv[j] = bias[n0 + wn * 64 + j * 16 + lr];
  #pragma unroll
  for (int i = 0; i < 8; i++) {
    const int row0 = m0 + wm * 128 + i * 16 + kq * 4;
    #pragma unroll
    for (int j = 0; j < 4; j++) {
      const int col = n0 + wn * 64 + j * 16 + lr;
      const float bvj = bv[j];
      #pragma unroll
      for (int r2 = 0; r2 < 4; r2++)
        C[(size_t)(row0 + r2) * 1024 + col] = acc[i][j][r2] + bvj;
    }
  }
}

// ---------------------------------------------------------------------------------
extern "C" void kernel_launch(void* const* d_in, const int* in_sizes, int n_in,
                              void* d_out, int out_size, void* d_ws, size_t ws_size,
                              hipStream_t stream) {
  (void)in_sizes; (void)n_in; (void)out_size; (void)ws_size;
  const float* x    = (const float*)d_in[0];
  const float* Wq   = (const float*)d_in[1];
  const float* Wkv  = (const float*)d_in[2];
  const float* Wlin = (const float*)d_in[3];
  const float* blin = (const float*)d_in[4];
  float* out = (float*)d_out;              // reference output dtype = float32

  // workspace layout (~160 MB total); all staged operands fragment-major
  bf16* x_bf  = (bf16*)d_ws;                  // 33,554,432
  bf16* WTc   = x_bf + 33554432;              // 3,145,728   [Wq^T | Wkv^T] frag-major
  bf16* WlinT = WTc + 3145728;                // 1,048,576   row-major (make_w2t)
  bf16* Yq    = WlinT + 1048576;              // 33,554,432  frag-major
  bf16* W2T   = Yq + 33554432;                // 8,388,608   frag-major
  float* ctxAcc = (float*)(W2T + 8388608);    // 128 * 4160 fp32 (R | Z)

  cast_x_frag<<<2048, 256, 0, stream>>>(x, x_bf);
  wcast_frag<<<dim3(4, 64), 256, 0, stream>>>(Wq, WTc, 1024, 0);
  wcast_frag<<<dim3(4, 128), 256, 0, stream>>>(Wkv, WTc, 2048, 1024);
  tcast<<<dim3(32, 32), dim3(32, 8), 0, stream>>>(Wlin, WlinT, 1024, 1024);

  hipMemsetAsync(ctxAcc, 0, (size_t)128 * 4160 * sizeof(float), stream);

  gemm_qkv<<<dim3(128 * QKV_NT), 512, 0, stream>>>(x_bf, WTc, Yq, ctxAcc);
  make_w2t<<<dim3(16, 128), 256, 0, stream>>>(ctxAcc, WlinT, W2T);
  gemm_out<<<dim3(512), 512, 0, stream>>>(Yq, W2T, out, blin);
}

// Round 10
// 378.997 us; speedup vs baseline: 5.7730x; 5.7730x over previous
//
#include <hip/hip_runtime.h>
#include <hip/hip_bf16.h>
#include <cstdint>

using bf16 = __hip_bfloat16;
typedef __attribute__((ext_vector_type(8))) short bf16x8;
typedef __attribute__((ext_vector_type(4))) float f32x4;

struct alignas(16) B8 { bf16 h[8]; };
struct alignas(8)  B4 { bf16 h[4]; };

__device__ __forceinline__ void gll16(const void* g, void* l) {
  __builtin_amdgcn_global_load_lds((__attribute__((address_space(1))) void*)g,
                                   (__attribute__((address_space(3))) void*)l,
                                   16, 0, 0);
}

// =================================================================================
// FRAGMENT-MAJOR GLOBAL LAYOUT: for a [rows][1024] operand, 16-B chunk id =
//   ((row>>4)*128 + (k>>3))*16 + (row&15)      (chunk content = 8 bf16 k-elems)
// Staging a 16-row group x 32-k section = 64 CONSECUTIVE chunks -> each gll16
// reads 1KB fully contiguous (perfect coalescing) and lands linearly in LDS in
// exactly fragment order -> frag ds_read_b128 = base + lane*16 (zero conflicts).
// =================================================================================

// ---------------- x fp32 [32768][1024] -> fragment-major bf16 ----------------
__global__ __launch_bounds__(256) void cast_x_frag(const float* __restrict__ x,
                                                   bf16* __restrict__ xr) {
  __shared__ float tile[16][257];
  const int g = blockIdx.x;                    // 16-row group, 0..2047
  const int t = threadIdx.x;
  const float* src = x + (size_t)g * 16384;    // 16 rows * 1024
  bf16* dst = xr + (size_t)g * 16384;          // 2048 chunks * 8 elems
  for (int kp = 0; kp < 4; ++kp) {
    const int k0 = kp * 256;
    if (kp) __syncthreads();
    {
      const int r = t >> 4, cl = t & 15;       // lanes 0..15 read 64B contiguous
      #pragma unroll
      for (int s = 0; s < 16; ++s)
        tile[r][cl + 16 * s] = src[(size_t)r * 1024 + k0 + cl + 16 * s];
    }
    __syncthreads();
    #pragma unroll
    for (int rd = 0; rd < 2; ++rd) {
      const int c = rd * 256 + t;
      const int ql = c >> 4, r = c & 15;       // bank = r + 8q + jj: conflict-free
      B8 o;
      #pragma unroll
      for (int jj = 0; jj < 8; ++jj) o.h[jj] = __float2bfloat16(tile[r][ql * 8 + jj]);
      *(B8*)(dst + ((size_t)(kp * 32 + ql) * 16 + r) * 8) = o;   // contiguous stores
    }
  }
}

// ---------------- W fp32 [K][N] -> fragment-major bf16 of W^T ----------------
// out chunk = (((n_glob0+n)>>4)*128 + (k>>3))*16 + (n&15)
__global__ __launch_bounds__(256) void wcast_frag(const float* __restrict__ W,
                                                  bf16* __restrict__ out,
                                                  int N, int n_glob0) {
  __shared__ float tw[256][17];
  const int k0 = blockIdx.x * 256;
  const int n0 = blockIdx.y * 16;
  const int t = threadIdx.x;
  {
    const int nn = t & 15, kk0 = t >> 4;       // lanes 0..15: 64B contiguous per row
    #pragma unroll
    for (int s = 0; s < 16; ++s) {
      const int kk = kk0 + 16 * s;
      tw[kk][nn] = W[(size_t)(k0 + kk) * N + n0 + nn];
    }
  }
  __syncthreads();
  const int ng = (n_glob0 + n0) >> 4;
  #pragma unroll
  for (int rd = 0; rd < 2; ++rd) {
    const int c = rd * 256 + t;
    const int ql = c >> 4, r = c & 15;         // bank = 8q + 17jj + r: free
    B8 o;
    #pragma unroll
    for (int jj = 0; jj < 8; ++jj) o.h[jj] = __float2bfloat16(tw[ql * 8 + jj][r]);
    *(B8*)(out + (((size_t)ng * 128 + (k0 >> 3) + ql) * 16 + r) * 8) = o;
  }
}

// ---------------- transpose + cast: W[K][N] fp32 -> WT[N][K] bf16 (row-major) ----
__global__ void tcast(const float* __restrict__ W, bf16* __restrict__ WT, int K, int N) {
  __shared__ float tile[32][33];
  int k0 = blockIdx.y * 32, n0 = blockIdx.x * 32;
  int tx = threadIdx.x, ty = threadIdx.y;  // block (32,8)
  for (int yy = ty; yy < 32; yy += 8)
    tile[yy][tx] = W[(size_t)(k0 + yy) * N + n0 + tx];
  __syncthreads();
  for (int yy = ty; yy < 32; yy += 8)
    WT[(size_t)(n0 + yy) * K + k0 + tx] = __float2bfloat16(tile[tx][yy]);
}

// =================================================================================
// 256x128-tile, BK=32-per-section, 4-WAVE (256-thread) main loop (K=1024).
// r10: 2 BLOCKS/CU via 4-wave blocks. r9's 2-block attempt spilled (launch_bounds
// (512,4) forced <=128 regs/wave vs ~230 needed -> VGPR=64, 7GB scratch). With
// 4-wave blocks at launch_bounds(256,2): <=256 regs/wave (fits, no spill),
// 2 waves/SIMD = 2 co-resident blocks/CU (LDS 64KB x2 = 128 <= 160KB). The two
// blocks have INDEPENDENT barriers -> when one drains vmcnt(0), the other's
// waves keep the MFMA pipe fed (m114: cross-wave pipe overlap, time ~ max).
// Per-section per wave: 6 gll16 stage (A:4, B:2), 12 ds_read_b128, 32 MFMA.
// Fragment-major operands: staging 1KB contiguous/gll16, frag reads conflict-free.
// Wave grid 2Mx2N: wm=wave>>1 (128-row half), wn=wave&1 (64-col half).
// =================================================================================
__device__ __forceinline__ void gemm_mainloop_256x128(
    const bf16* __restrict__ aop, const bf16* __restrict__ bop,
    bf16* ldsA, bf16* ldsB, int wdA, int wdB,
    int aoff, int boff, f32x4 (&acc)[8][4])
{
  // A slot = 16 groups x 512 elems (16KB); B slot = 8 groups x 512 (8KB).
  // Wave stages A groups {w, w+4, w+8, w+12}, B groups {w, w+4}.
#define STAGE(slot, ko) do {                                                        \
    gll16(aop + (ko) * 16,          ldsA + (slot) * 8192 + wdA);                    \
    gll16(aop + (ko) * 16 + 65536,  ldsA + (slot) * 8192 + wdA + 2048);             \
    gll16(aop + (ko) * 16 + 131072, ldsA + (slot) * 8192 + wdA + 4096);             \
    gll16(aop + (ko) * 16 + 196608, ldsA + (slot) * 8192 + wdA + 6144);             \
    gll16(bop + (ko) * 16,          ldsB + (slot) * 4096 + wdB);                    \
    gll16(bop + (ko) * 16 + 65536,  ldsB + (slot) * 4096 + wdB + 2048);             \
  } while (0)
#define AFRAG(slot, i) (*(const bf16x8*)(ldsA + (slot) * 8192 + aoff + (i) * 512))
#define BFRAG(slot, j) (*(const bf16x8*)(ldsB + (slot) * 4096 + boff + (j) * 512))

  bf16x8 a1[4], a2[4], bb[4];

  // prologue: stage slot 0, drain, sync
  STAGE(0, 0);
  asm volatile("s_waitcnt vmcnt(0)" ::: "memory");
  __builtin_amdgcn_s_barrier();
  __builtin_amdgcn_sched_barrier(0);

  #pragma unroll 2
  for (int v = 0; v < 32; ++v) {
    const int s = v & 1;
    if (v < 31) STAGE(s ^ 1, (v + 1) * 32);
    #pragma unroll
    for (int j = 0; j < 4; j++) bb[j] = BFRAG(s, j);
    #pragma unroll
    for (int i = 0; i < 4; i++) a1[i] = AFRAG(s, i);
    asm volatile("s_waitcnt lgkmcnt(0)" ::: "memory");
    __builtin_amdgcn_sched_barrier(0);
    __builtin_amdgcn_s_setprio(1);
    #pragma unroll
    for (int i = 0; i < 4; i++) {
      #pragma unroll
      for (int j = 0; j < 4; j++)
        acc[i][j] = __builtin_amdgcn_mfma_f32_16x16x32_bf16(a1[i], bb[j], acc[i][j], 0, 0, 0);
      a2[i] = AFRAG(s, i + 4);
    }
    asm volatile("s_waitcnt lgkmcnt(0)" ::: "memory");
    __builtin_amdgcn_sched_barrier(0);
    #pragma unroll
    for (int i = 0; i < 4; i++)
      #pragma unroll
      for (int j = 0; j < 4; j++)
        acc[i + 4][j] = __builtin_amdgcn_mfma_f32_16x16x32_bf16(a2[i], bb[j], acc[i + 4][j], 0, 0, 0);
    __builtin_amdgcn_s_setprio(0);
    asm volatile("s_waitcnt vmcnt(0)" ::: "memory");
    __builtin_amdgcn_s_barrier();
    __builtin_amdgcn_sched_barrier(0);
  }
#undef STAGE
#undef AFRAG
#undef BFRAG
}

// =================================================================================
// Fused QKV GEMM:  T = x_bf @ [Wq | Wkv]  (M=32768, N=3072, K=1024)
//  - grid 128 bm x 24 bn = 3072 blocks (256 thr); XCD swizzle 3072 = 8 x 384.
//  - q tiles (bn<8): wave's 64 cols (n0+wn*64) = one head; per-row softmax,
//    * DH^-0.5; Yq written FRAGMENT-MAJOR.
//  - kv tiles (bn>=8): tile = 256 s-rows x 1 head (cols 0-63 = k, 64-127 = v);
//    wn picks operand. exp(k)/v -> swizzled LDS [64][256]; Z register-resident
//    (shfl reduce + atomics); R[d][e]: 4 waves = 4 d-quads over K=256; atomics.
// =================================================================================
constexpr int QKV_NT = 24;   // N/128

__global__ __launch_bounds__(256, 2)
void gemm_qkv(const bf16* __restrict__ A, const bf16* __restrict__ BT,
              bf16* __restrict__ Yq, float* __restrict__ ctxAcc)
{
  __shared__ __align__(16) union {
    struct { bf16 a[2 * 8192]; bf16 b[2 * 4096]; } g;   // 48 KB staging
    struct { bf16 ekT[16384]; bf16 vT[16384]; } c;      // 64 KB kv epilogue
  } sm;

  const int t = threadIdx.x;
  const int wave = t >> 6, lane = t & 63;
  const int lr = lane & 15, kq = lane >> 4;
  const int wm = wave >> 1, wn = wave & 1;
  // XCD-chunked swizzle (bijective: 3072 = 8 * 384; dispatch round-robins bid%8)
  const int bid = (int)blockIdx.x;
  const int swz = (bid & 7) * 384 + (bid >> 3);
  const int bm = swz / QKV_NT, bn = swz % QKV_NT;
  const int m0 = bm * 256, n0 = bn * 128;

  const bf16* aop = A + (size_t)((m0 >> 4) + wave) * 16384 + lane * 8;
  const bf16* bop = BT + (size_t)((n0 >> 4) + wave) * 16384 + lane * 8;
  const int wdA = wave * 512, wdB = wave * 512;
  const int aoff = wm * 4096 + lane * 8;   // + i*512 per i-tile
  const int boff = wn * 2048 + lane * 8;   // + j*512 per j-tile

  const f32x4 zero = {0.f, 0.f, 0.f, 0.f};
  f32x4 acc[8][4];
  #pragma unroll
  for (int i = 0; i < 8; i++)
    #pragma unroll
    for (int j = 0; j < 4; j++) acc[i][j] = zero;

  gemm_mainloop_256x128(aop, bop, sm.g.a, sm.g.b, wdA, wdB, aoff, boff, acc);

  if (bn < 8) {
    // ---- fused q softmax; Yq written fragment-major ----
    const int qb = (n0 + wn * 64) >> 3;
    const int jo = (lr >> 3) * 128;
    #pragma unroll
    for (int i = 0; i < 8; i++) {
      #pragma unroll
      for (int r = 0; r < 4; r++) {
        float m = fmaxf(fmaxf(acc[i][0][r], acc[i][1][r]),
                        fmaxf(acc[i][2][r], acc[i][3][r]));
        m = fmaxf(m, __shfl_xor(m, 1));
        m = fmaxf(m, __shfl_xor(m, 2));
        m = fmaxf(m, __shfl_xor(m, 4));
        m = fmaxf(m, __shfl_xor(m, 8));
        float ex[4]; float s = 0.f;
        #pragma unroll
        for (int j = 0; j < 4; j++) { ex[j] = __expf(acc[i][j][r] - m); s += ex[j]; }
        s += __shfl_xor(s, 1);
        s += __shfl_xor(s, 2);
        s += __shfl_xor(s, 4);
        s += __shfl_xor(s, 8);
        const float inv = 0.125f / s;           // scale = DH^-0.5
        const int row = m0 + wm * 128 + i * 16 + kq * 4 + r;
        bf16* yb = Yq + (((size_t)(row >> 4) * 128 + qb) * 16 + (row & 15)) * 8 + (lr & 7);
        #pragma unroll
        for (int j = 0; j < 4; j++)
          yb[j * 256 + jo] = __float2bfloat16(ex[j] * inv);
      }
    }
  } else {
    // ---- fused context: tile = 256 s-rows x 1 head (64 k | 64 v) ----
    const int bb2 = m0 >> 12;                 // batch (4096 rows per batch)
    const int h = bn - 8;                     // head 0..15
    bf16* const dstT = (wn ? sm.c.vT : sm.c.ekT);

    float zp[4] = {0.f, 0.f, 0.f, 0.f};
    #pragma unroll
    for (int i = 0; i < 8; i++) {
      const int sbase = wm * 128 + i * 16 + kq * 4;
      const int sxo = sbase >> 3;             // chunk (constant across r)
      const int sby = (sbase & 7) * 2;        // byte offset within chunk (0 or 8)
      #pragma unroll
      for (int j = 0; j < 4; j++) {
        const int d = j * 16 + lr;
        B4 pk;
        if (!wn) {
          #pragma unroll
          for (int r = 0; r < 4; r++) {
            float e = __expf(acc[i][j][r]);
            zp[j] += e;
            pk.h[r] = __float2bfloat16(e);
          }
        } else {
          #pragma unroll
          for (int r = 0; r < 4; r++) pk.h[r] = __float2bfloat16(acc[i][j][r]);
        }
        *(B4*)((char*)dstT + d * 512 + ((sxo ^ (d & 7)) << 4) + sby) = pk;
      }
    }
    __syncthreads();

    // R[d][e] partial via MFMA over K=256 s-rows; wave = d-quad
    const int dq = wave;
    f32x4 racc[4] = {zero, zero, zero, zero};
    #pragma unroll
    for (int ks = 0; ks < 8; ks++) {
      const int ch = ks * 4 + kq;
      bf16x8 af = *(const bf16x8*)((const char*)sm.c.ekT + (dq * 16 + lr) * 512 + ((ch ^ (lr & 7)) << 4));
      #pragma unroll
      for (int j = 0; j < 4; j++) {
        bf16x8 bfr = *(const bf16x8*)((const char*)sm.c.vT + (j * 16 + lr) * 512 + ((ch ^ (lr & 7)) << 4));
        racc[j] = __builtin_amdgcn_mfma_f32_16x16x32_bf16(af, bfr, racc[j], 0, 0, 0);
      }
    }
    float* cb = ctxAcc + (size_t)(bb2 * 16 + h) * 4160;
    #pragma unroll
    for (int j = 0; j < 4; j++) {
      #pragma unroll
      for (int r = 0; r < 4; r++)
        atomicAdd(cb + (dq * 16 + kq * 4 + r) * 64 + j * 16 + lr, racc[j][r]);
    }

    if (!wn) {
      // Z[d] partial over this wave's 128 s-rows, straight from registers
      #pragma unroll
      for (int j = 0; j < 4; j++) {
        zp[j] += __shfl_xor(zp[j], 16);
        zp[j] += __shfl_xor(zp[j], 32);
      }
      if (kq == 0) {
        float* zb = cb + 4096;
        #pragma unroll
        for (int j = 0; j < 4; j++) atomicAdd(zb + j * 16 + lr, zp[j]);
      }
    }
  }
}

// ---------------- W2T[b] = (R/Z) @ WlinT-slice, written FRAGMENT-MAJOR ----------
__global__ __launch_bounds__(256) void make_w2t(const float* __restrict__ ctxAcc,
                                                const bf16* __restrict__ WlinT,
                                                bf16* __restrict__ W2T) {
  const int nc = blockIdx.x;      // 0..15
  const int bh = blockIdx.y;      // 0..127
  const int b = bh >> 4, h = bh & 15;
  const int t = threadIdx.x, lane = t & 63, w = t >> 6;
  const float* src = ctxAcc + (size_t)bh * 4160;
  const float invz = 1.0f / src[4096 + lane];   // Z[d], d = lane
  float creg[64];
  const float* crow = src + lane * 64;
  #pragma unroll
  for (int e4 = 0; e4 < 16; e4++) {
    float4 v = *(const float4*)(crow + e4 * 4);
    creg[e4 * 4 + 0] = v.x * invz; creg[e4 * 4 + 1] = v.y * invz;
    creg[e4 * 4 + 2] = v.z * invz; creg[e4 * 4 + 3] = v.w * invz;
  }
  for (int i = 0; i < 16; i++) {
    const int n = nc * 64 + w * 16 + i;
    const bf16* wrow = WlinT + (size_t)n * 1024 + h * 64;
    float acc = 0.f;
    #pragma unroll
    for (int e8 = 0; e8 < 8; e8++) {
      B8 v = *(const B8*)(wrow + e8 * 8);
      #pragma unroll
      for (int j = 0; j < 8; j++) acc += creg[e8 * 8 + j] * __bfloat162float(v.h[j]);
    }
    // fragment-major: col = h*64+lane -> q = h*8 + (lane>>3), e = lane&7
    W2T[(size_t)b * 1048576 +
        (((size_t)(n >> 4) * 128 + h * 8 + (lane >> 3)) * 16 + (n & 15)) * 8 + (lane & 7)]
        = __float2bfloat16(acc);
  }
}

// ---------------- out[b] = Yq[b] @ W2T[b]^T + blin, fp32 output -------------------
// per batch: M=4096(16 bm), N=1024(8 bn); 256x128 tiles, 256 thr; grid 1024.
// XCD swizzle: 1024 = 8 x 128; each XCD owns one batch (W2T[b] 2MB L2-resident).
__global__ __launch_bounds__(256, 2)
void gemm_out(const bf16* __restrict__ Aall, const bf16* __restrict__ BTall,
              float* __restrict__ Call, const float* __restrict__ bias)
{
  __shared__ __align__(16) struct { bf16 a[2 * 8192]; bf16 b[2 * 4096]; } sm;
  const int t = threadIdx.x;
  const int wave = t >> 6, lane = t & 63;
  const int lr = lane & 15, kq = lane >> 4;
  const int wm = wave >> 1, wn = wave & 1;
  const int bid = (int)blockIdx.x;
  const int swz = (bid & 7) * 128 + (bid >> 3);
  const int bz = swz >> 7;
  const int r  = swz & 127;
  const int bm = r >> 3, bn = r & 7;
  const int m0 = bm * 256, n0 = bn * 128;
  const bf16* A  = Aall  + (size_t)bz * 4194304;
  const bf16* BT = BTall + (size_t)bz * 1048576;
  float* C       = Call  + (size_t)bz * 4194304;

  const bf16* aop = A + (size_t)((m0 >> 4) + wave) * 16384 + lane * 8;
  const bf16* bop = BT + (size_t)((n0 >> 4) + wave) * 16384 + lane * 8;
  const int wdA = wave * 512, wdB = wave * 512;
  const int aoff = wm * 4096 + lane * 8;
  const int boff = wn * 2048 + lane * 8;

  const f32x4 zero = {0.f, 0.f, 0.f, 0.f};
  f32x4 acc[8][4];
  #pragma unroll
  for (int i = 0; i < 8; i++)
    #pragma unroll
    for (int j = 0; j < 4; j++) acc[i][j] = zero;

  gemm_mainloop_256x128(aop, bop, sm.a, sm.b, wdA, wdB, aoff, boff, acc);

  float bv[4];
  #pragma unroll
  for (int j = 0; j < 4; j++) bv[j] = bias[n0 + wn * 64 + j * 16 + lr];
  #pragma unroll
  for (int i = 0; i < 8; i++) {
    const int row0 = m0 + wm * 128 + i * 16 + kq * 4;
    #pragma unroll
    for (int j = 0; j < 4; j++) {
      const int col = n0 + wn * 64 + j * 16 + lr;
      const float bvj = bv[j];
      #pragma unroll
      for (int r2 = 0; r2 < 4; r2++)
        C[(size_t)(row0 + r2) * 1024 + col] = acc[i][j][r2] + bvj;
    }
  }
}

// ---------------------------------------------------------------------------------
extern "C" void kernel_launch(void* const* d_in, const int* in_sizes, int n_in,
                              void* d_out, int out_size, void* d_ws, size_t ws_size,
                              hipStream_t stream) {
  (void)in_sizes; (void)n_in; (void)out_size; (void)ws_size;
  const float* x    = (const float*)d_in[0];
  const float* Wq   = (const float*)d_in[1];
  const float* Wkv  = (const float*)d_in[2];
  const float* Wlin = (const float*)d_in[3];
  const float* blin = (const float*)d_in[4];
  float* out = (float*)d_out;              // reference output dtype = float32

  // workspace layout (~160 MB total); all staged operands fragment-major
  bf16* x_bf  = (bf16*)d_ws;                  // 33,554,432
  bf16* WTc   = x_bf + 33554432;              // 3,145,728   [Wq^T | Wkv^T] frag-major
  bf16* WlinT = WTc + 3145728;                // 1,048,576   row-major (make_w2t)
  bf16* Yq    = WlinT + 1048576;              // 33,554,432  frag-major
  bf16* W2T   = Yq + 33554432;                // 8,388,608   frag-major
  float* ctxAcc = (float*)(W2T + 8388608);    // 128 * 4160 fp32 (R | Z)

  cast_x_frag<<<2048, 256, 0, stream>>>(x, x_bf);
  wcast_frag<<<dim3(4, 64), 256, 0, stream>>>(Wq, WTc, 1024, 0);
  wcast_frag<<<dim3(4, 128), 256, 0, stream>>>(Wkv, WTc, 2048, 1024);
  tcast<<<dim3(32, 32), dim3(32, 8), 0, stream>>>(Wlin, WlinT, 1024, 1024);

  hipMemsetAsync(ctxAcc, 0, (size_t)128 * 4160 * sizeof(float), stream);

  gemm_qkv<<<dim3(128 * QKV_NT), 256, 0, stream>>>(x_bf, WTc, Yq, ctxAcc);
  make_w2t<<<dim3(16, 128), 256, 0, stream>>>(ctxAcc, WlinT, W2T);
  gemm_out<<<dim3(1024), 256, 0, stream>>>(Yq, W2T, out, blin);
}

// Round 11
// 371.338 us; speedup vs baseline: 5.8921x; 1.0206x over previous
//
#include <hip/hip_runtime.h>
#include <hip/hip_bf16.h>
#include <cstdint>

using bf16 = __hip_bfloat16;
typedef __attribute__((ext_vector_type(8))) short bf16x8;
typedef __attribute__((ext_vector_type(4))) float f32x4;

struct alignas(16) B8 { bf16 h[8]; };
struct alignas(8)  B4 { bf16 h[4]; };

__device__ __forceinline__ void gll16(const void* g, void* l) {
  __builtin_amdgcn_global_load_lds((__attribute__((address_space(1))) void*)g,
                                   (__attribute__((address_space(3))) void*)l,
                                   16, 0, 0);
}

// =================================================================================
// FRAGMENT-MAJOR GLOBAL LAYOUT: for a [rows][1024] operand, 16-B chunk id =
//   ((row>>4)*128 + (k>>3))*16 + (row&15)      (chunk content = 8 bf16 k-elems)
// Staging a 16-row group x 32-k section = 64 CONSECUTIVE chunks -> each gll16
// reads 1KB fully contiguous (perfect coalescing) and lands linearly in LDS in
// exactly fragment order -> frag ds_read_b128 = base + lane*16 (zero conflicts).
// =================================================================================

// ---------------- x fp32 [32768][1024] -> fragment-major bf16 ----------------
__global__ __launch_bounds__(256) void cast_x_frag(const float* __restrict__ x,
                                                   bf16* __restrict__ xr) {
  __shared__ float tile[16][257];
  const int g = blockIdx.x;                    // 16-row group, 0..2047
  const int t = threadIdx.x;
  const float* src = x + (size_t)g * 16384;    // 16 rows * 1024
  bf16* dst = xr + (size_t)g * 16384;          // 2048 chunks * 8 elems
  for (int kp = 0; kp < 4; ++kp) {
    const int k0 = kp * 256;
    if (kp) __syncthreads();
    {
      const int r = t >> 4, cl = t & 15;       // lanes 0..15 read 64B contiguous
      #pragma unroll
      for (int s = 0; s < 16; ++s)
        tile[r][cl + 16 * s] = src[(size_t)r * 1024 + k0 + cl + 16 * s];
    }
    __syncthreads();
    #pragma unroll
    for (int rd = 0; rd < 2; ++rd) {
      const int c = rd * 256 + t;
      const int ql = c >> 4, r = c & 15;       // bank = r + 8q + jj: conflict-free
      B8 o;
      #pragma unroll
      for (int jj = 0; jj < 8; ++jj) o.h[jj] = __float2bfloat16(tile[r][ql * 8 + jj]);
      *(B8*)(dst + ((size_t)(kp * 32 + ql) * 16 + r) * 8) = o;   // contiguous stores
    }
  }
}

// ---------------- W fp32 [K][N] -> fragment-major bf16 of W^T ----------------
// out chunk = (((n_glob0+n)>>4)*128 + (k>>3))*16 + (n&15)
__global__ __launch_bounds__(256) void wcast_frag(const float* __restrict__ W,
                                                  bf16* __restrict__ out,
                                                  int N, int n_glob0) {
  __shared__ float tw[256][17];
  const int k0 = blockIdx.x * 256;
  const int n0 = blockIdx.y * 16;
  const int t = threadIdx.x;
  {
    const int nn = t & 15, kk0 = t >> 4;       // lanes 0..15: 64B contiguous per row
    #pragma unroll
    for (int s = 0; s < 16; ++s) {
      const int kk = kk0 + 16 * s;
      tw[kk][nn] = W[(size_t)(k0 + kk) * N + n0 + nn];
    }
  }
  __syncthreads();
  const int ng = (n_glob0 + n0) >> 4;
  #pragma unroll
  for (int rd = 0; rd < 2; ++rd) {
    const int c = rd * 256 + t;
    const int ql = c >> 4, r = c & 15;         // bank = 8q + 17jj + r: free
    B8 o;
    #pragma unroll
    for (int jj = 0; jj < 8; ++jj) o.h[jj] = __float2bfloat16(tw[ql * 8 + jj][r]);
    *(B8*)(out + (((size_t)ng * 128 + (k0 >> 3) + ql) * 16 + r) * 8) = o;
  }
}

// ---------------- transpose + cast: W[K][N] fp32 -> WT[N][K] bf16 (row-major) ----
__global__ void tcast(const float* __restrict__ W, bf16* __restrict__ WT, int K, int N) {
  __shared__ float tile[32][33];
  int k0 = blockIdx.y * 32, n0 = blockIdx.x * 32;
  int tx = threadIdx.x, ty = threadIdx.y;  // block (32,8)
  for (int yy = ty; yy < 32; yy += 8)
    tile[yy][tx] = W[(size_t)(k0 + yy) * N + n0 + tx];
  __syncthreads();
  for (int yy = ty; yy < 32; yy += 8)
    WT[(size_t)(n0 + yy) * K + k0 + tx] = __float2bfloat16(tile[tx][yy]);
}

// =================================================================================
// Shared 256x256-tile, BK=32-per-section, 8-wave pipelined main loop (K=1024).
// Fragment-major operands; zero-conflict frag reads. Staging gll16 ops are
// interleaved into the MFMA clusters; boundary = vmcnt(4) + s_barrier only.
// Section v consumes slot v&3, prefetches (v+1)&3, stages (v+3)&3 in-cluster.
// (r8 configuration — best measured: gemm_qkv 200.7 us, MfmaUtil 46.8%.)
// =================================================================================
__device__ __forceinline__ void gemm_mainloop_256(
    const bf16* __restrict__ aop0, const bf16* __restrict__ aop1,
    const bf16* __restrict__ bop0, const bf16* __restrict__ bop1,
    bf16* ldsA, bf16* ldsB, int wd0, int wd1,
    int aoff, int boff, f32x4 (&acc)[8][4])
{
#define STAGE_A(slot, ko) do { gll16(aop0 + (ko) * 16, ldsA + (slot) * 8192 + wd0); \
                               gll16(aop1 + (ko) * 16, ldsA + (slot) * 8192 + wd1); } while (0)
#define STAGE_B(slot, ko) do { gll16(bop0 + (ko) * 16, ldsB + (slot) * 8192 + wd0); \
                               gll16(bop1 + (ko) * 16, ldsB + (slot) * 8192 + wd1); } while (0)
#define AFRAG(slot, i) (*(const bf16x8*)(ldsA + (slot) * 8192 + aoff + (i) * 512))
#define BFRAG(slot, j) (*(const bf16x8*)(ldsB + (slot) * 8192 + boff + (j) * 512))

  bf16x8 a1[4], a2[4], bb[2][4];

#define SECTION(S, CURB, NXTB, DO_PF, PFS, DO_ST, SLOT, KO)                         \
  do {                                                                              \
    asm volatile("s_waitcnt lgkmcnt(0)" ::: "memory");                              \
    __builtin_amdgcn_sched_barrier(0);                                              \
    __builtin_amdgcn_s_setprio(1);                                                  \
    _Pragma("unroll")                                                               \
    for (int i = 0; i < 4; i++) {                                                   \
      _Pragma("unroll")                                                             \
      for (int j = 0; j < 4; j++)                                                   \
        acc[i][j] = __builtin_amdgcn_mfma_f32_16x16x32_bf16(a1[i], bb[CURB][j],     \
                                                            acc[i][j], 0, 0, 0);    \
      a2[i] = AFRAG(S, i + 4);                                                      \
      if (DO_ST && i == 0) gll16(aop0 + (KO) * 16, ldsA + (SLOT) * 8192 + wd0);     \
      if (DO_ST && i == 1) gll16(aop1 + (KO) * 16, ldsA + (SLOT) * 8192 + wd1);     \
    }                                                                               \
    asm volatile("s_waitcnt lgkmcnt(0)" ::: "memory");                              \
    __builtin_amdgcn_sched_barrier(0);                                              \
    _Pragma("unroll")                                                               \
    for (int i = 0; i < 4; i++) {                                                   \
      _Pragma("unroll")                                                             \
      for (int j = 0; j < 4; j++)                                                   \
        acc[i + 4][j] = __builtin_amdgcn_mfma_f32_16x16x32_bf16(a2[i], bb[CURB][j], \
                                                                acc[i + 4][j], 0, 0, 0); \
      if (DO_PF) { bb[NXTB][i] = BFRAG(PFS, i); a1[i] = AFRAG(PFS, i); }            \
      if (DO_ST && i == 0) gll16(bop0 + (KO) * 16, ldsB + (SLOT) * 8192 + wd0);     \
      if (DO_ST && i == 1) gll16(bop1 + (KO) * 16, ldsB + (SLOT) * 8192 + wd1);     \
    }                                                                               \
    __builtin_amdgcn_s_setprio(0);                                                  \
  } while (0)

#define BOUNDARY(VMC)                                                               \
  do {                                                                              \
    asm volatile("s_waitcnt vmcnt(" #VMC ")" ::: "memory");                         \
    __builtin_amdgcn_s_barrier();                                                   \
    __builtin_amdgcn_sched_barrier(0);                                              \
  } while (0)

  // prologue: stage slots 0,1,2; retire 0,1 (slot 2 stays in flight = steady state)
  STAGE_A(0, 0);  STAGE_B(0, 0);
  STAGE_A(1, 32); STAGE_B(1, 32);
  STAGE_A(2, 64); STAGE_B(2, 64);
  asm volatile("s_waitcnt vmcnt(4)" ::: "memory");
  __builtin_amdgcn_s_barrier();
  __builtin_amdgcn_sched_barrier(0);
  #pragma unroll
  for (int j = 0; j < 4; j++) bb[0][j] = BFRAG(0, j);
  #pragma unroll
  for (int i = 0; i < 4; i++) a1[i] = AFRAG(0, i);

  // sections 0..27: section v consumes slot v&3, prefetches slot (v+1)&3,
  // stages slot (v+3)&3 at ko=(v+3)*32 inside its MFMA clusters.
  for (int q = 0; q < 7; ++q) {
    const int ko = q * 128;
    SECTION(0, 0, 1, true, 1, true, 3, ko + 96);
    BOUNDARY(4);
    SECTION(1, 1, 0, true, 2, true, 0, ko + 128);
    BOUNDARY(4);
    SECTION(2, 0, 1, true, 3, true, 1, ko + 160);
    BOUNDARY(4);
    SECTION(3, 1, 0, true, 0, true, 2, ko + 192);
    BOUNDARY(4);
  }
  // tail: v=28 (stages last chunk ko=992 -> slot 3), then drain
  SECTION(0, 0, 1, true, 1, true, 3, 992);
  BOUNDARY(4);
  SECTION(1, 1, 0, true, 2, false, 0, 0);
  BOUNDARY(0);
  SECTION(2, 0, 1, true, 3, false, 0, 0);
  BOUNDARY(0);
  SECTION(3, 1, 0, false, 0, false, 0, 0);

  __syncthreads();   // all frag reads done before epilogues reuse/overwrite LDS
#undef SECTION
#undef BOUNDARY
#undef STAGE_A
#undef STAGE_B
#undef AFRAG
#undef BFRAG
}

// =================================================================================
// Fused QKV GEMM:  T = x_bf @ [Wq | Wkv]  (M=32768, N=3072, K=1024)
//  - all operands fragment-major; XCD-chunked swizzle 1536 = 8 x 192 (bm-major).
//  - q tiles (bn<4): per-row softmax over the wave's 64-col head slice (* DH^-0.5);
//    Yq written FRAGMENT-MAJOR (consumed by gemm_out staging).
//  - kv tiles: 2 heads/block. exp(k), v -> swizzled LDS [64][256] via b64 writes;
//    Z from registers (shfl reduce); R[d][e] partial via MFMA; fp32 atomics.
// =================================================================================
constexpr int QKV_NT = 12;   // N/256

__global__ __launch_bounds__(512, 2)
void gemm_qkv(const bf16* __restrict__ A, const bf16* __restrict__ BT,
              bf16* __restrict__ Yq, float* __restrict__ ctxAcc)
{
  __shared__ __align__(16) union {
    struct { bf16 a[4 * 8192]; bf16 b[4 * 8192]; } g;       // 4+4 slots (16KB each)
    struct { bf16 ekT[2][16384]; bf16 vT[2][16384]; } c;    // kv epilogue (swizzled [64][256])
  } sm;

  const int t = threadIdx.x;
  const int wave = t >> 6, lane = t & 63;
  const int lr = lane & 15, kq = lane >> 4;
  const int wm = wave >> 2, wn = wave & 3;
  // XCD-chunked swizzle (bijective: 1536 = 8 * 192; dispatch round-robins bid%8)
  const int bid = (int)blockIdx.x;
  const int swz = (bid & 7) * 192 + (bid >> 3);
  const int bm = swz / QKV_NT, bn = swz % QKV_NT;
  const int m0 = bm * 256, n0 = bn * 256;

  // ---- staging pointers: wave stages 16-row group (m0>>4)+wave (+8 for aop1);
  //      lane sources chunk base + lane (1KB contiguous per gll16).
  const bf16* aop0 = A + (size_t)((m0 >> 4) + wave) * 16384 + lane * 8;
  const bf16* aop1 = aop0 + 131072;
  const bf16* bop0 = BT + (size_t)((n0 >> 4) + wave) * 16384 + lane * 8;
  const bf16* bop1 = bop0 + 131072;
  const int wd0 = wave * 512;          // elems, wave-uniform dest (gll writes base+lane*16)
  const int wd1 = 4096 + wave * 512;

  // ---- fragment-read offsets (contiguous 1KB per frag; lane*8 elems within)
  const int aoff = wm * 4096 + lane * 8;   // + i*512 per i-tile
  const int boff = wn * 2048 + lane * 8;   // + j*512 per j-tile

  const f32x4 zero = {0.f, 0.f, 0.f, 0.f};
  f32x4 acc[8][4];
  #pragma unroll
  for (int i = 0; i < 8; i++)
    #pragma unroll
    for (int j = 0; j < 4; j++) acc[i][j] = zero;

  gemm_mainloop_256(aop0, aop1, bop0, bop1, sm.g.a, sm.g.b, wd0, wd1,
                    aoff, boff, acc);

  if (bn < 4) {
    // ---- fused q softmax; Yq written fragment-major ----
    const int qb = (n0 + wn * 64) >> 3;
    const int jo = (lr >> 3) * 128;
    #pragma unroll
    for (int i = 0; i < 8; i++) {
      #pragma unroll
      for (int r = 0; r < 4; r++) {
        float m = fmaxf(fmaxf(acc[i][0][r], acc[i][1][r]),
                        fmaxf(acc[i][2][r], acc[i][3][r]));
        m = fmaxf(m, __shfl_xor(m, 1));
        m = fmaxf(m, __shfl_xor(m, 2));
        m = fmaxf(m, __shfl_xor(m, 4));
        m = fmaxf(m, __shfl_xor(m, 8));
        float ex[4]; float s = 0.f;
        #pragma unroll
        for (int j = 0; j < 4; j++) { ex[j] = __expf(acc[i][j][r] - m); s += ex[j]; }
        s += __shfl_xor(s, 1);
        s += __shfl_xor(s, 2);
        s += __shfl_xor(s, 4);
        s += __shfl_xor(s, 8);
        const float inv = 0.125f / s;           // scale = DH^-0.5
        const int row = m0 + wm * 128 + i * 16 + kq * 4 + r;
        bf16* yb = Yq + (((size_t)(row >> 4) * 128 + qb) * 16 + (row & 15)) * 8 + (lr & 7);
        #pragma unroll
        for (int j = 0; j < 4; j++)
          yb[j * 256 + jo] = __float2bfloat16(ex[j] * inv);
      }
    }
  } else {
    // ---- fused context: tile = 256 s-rows x 2 heads (each head: 64 k | 64 v) ----
    const int bb2 = m0 >> 12;                 // batch (4096 rows per batch)
    const int h0 = (n0 - 1024) >> 7;          // first head of this tile
    const int hloc = wn >> 1, isV = wn & 1;   // wave role
    bf16* const dstT = (isV ? sm.c.vT[hloc] : sm.c.ekT[hloc]);

    float zp[4] = {0.f, 0.f, 0.f, 0.f};
    #pragma unroll
    for (int i = 0; i < 8; i++) {
      const int sbase = wm * 128 + i * 16 + kq * 4;
      const int sxo = sbase >> 3;             // chunk (constant across r)
      const int sby = (sbase & 7) * 2;        // byte offset within chunk (0 or 8)
      #pragma unroll
      for (int j = 0; j < 4; j++) {
        const int d = j * 16 + lr;
        B4 pk;
        if (!isV) {
          #pragma unroll
          for (int r = 0; r < 4; r++) {
            float e = __expf(acc[i][j][r]);
            zp[j] += e;
            pk.h[r] = __float2bfloat16(e);
          }
        } else {
          #pragma unroll
          for (int r = 0; r < 4; r++) pk.h[r] = __float2bfloat16(acc[i][j][r]);
        }
        *(B4*)((char*)dstT + d * 512 + ((sxo ^ (d & 7)) << 4) + sby) = pk;
      }
    }

    if (!isV) {
      // Z[d] partial over this wave's 128 s-rows, straight from registers
      #pragma unroll
      for (int j = 0; j < 4; j++) {
        zp[j] += __shfl_xor(zp[j], 16);
        zp[j] += __shfl_xor(zp[j], 32);
      }
      if (kq == 0) {
        float* zb = ctxAcc + (size_t)(bb2 * 16 + h0 + hloc) * 4160 + 4096;
        #pragma unroll
        for (int j = 0; j < 4; j++) atomicAdd(zb + j * 16 + lr, zp[j]);
      }
    }
    __syncthreads();

    // R[d][e] partial via MFMA over K=256 s-rows; wave -> (head = wave>>2, d-quad = wave&3)
    const int hh = wave >> 2, dq = wave & 3;
    const bf16* const ek = sm.c.ekT[hh];
    const bf16* const vv = sm.c.vT[hh];
    f32x4 racc[4] = {zero, zero, zero, zero};
    #pragma unroll
    for (int ks = 0; ks < 8; ks++) {
      const int ch = ks * 4 + kq;
      bf16x8 af = *(const bf16x8*)((const char*)ek + (dq * 16 + lr) * 512 + ((ch ^ (lr & 7)) << 4));
      #pragma unroll
      for (int j = 0; j < 4; j++) {
        bf16x8 bfr = *(const bf16x8*)((const char*)vv + (j * 16 + lr) * 512 + ((ch ^ (lr & 7)) << 4));
        racc[j] = __builtin_amdgcn_mfma_f32_16x16x32_bf16(af, bfr, racc[j], 0, 0, 0);
      }
    }
    float* cb = ctxAcc + (size_t)(bb2 * 16 + h0 + hh) * 4160;
    #pragma unroll
    for (int j = 0; j < 4; j++) {
      #pragma unroll
      for (int r = 0; r < 4; r++)
        atomicAdd(cb + (dq * 16 + kq * 4 + r) * 64 + j * 16 + lr, racc[j][r]);
    }
  }
}

// ---------------- W2T[b] = (R/Z) @ WlinT-slice, written FRAGMENT-MAJOR ----------
__global__ __launch_bounds__(256) void make_w2t(const float* __restrict__ ctxAcc,
                                                const bf16* __restrict__ WlinT,
                                                bf16* __restrict__ W2T) {
  const int nc = blockIdx.x;      // 0..15
  const int bh = blockIdx.y;      // 0..127
  const int b = bh >> 4, h = bh & 15;
  const int t = threadIdx.x, lane = t & 63, w = t >> 6;
  const float* src = ctxAcc + (size_t)bh * 4160;
  const float invz = 1.0f / src[4096 + lane];   // Z[d], d = lane
  float creg[64];
  const float* crow = src + lane * 64;
  #pragma unroll
  for (int e4 = 0; e4 < 16; e4++) {
    float4 v = *(const float4*)(crow + e4 * 4);
    creg[e4 * 4 + 0] = v.x * invz; creg[e4 * 4 + 1] = v.y * invz;
    creg[e4 * 4 + 2] = v.z * invz; creg[e4 * 4 + 3] = v.w * invz;
  }
  for (int i = 0; i < 16; i++) {
    const int n = nc * 64 + w * 16 + i;
    const bf16* wrow = WlinT + (size_t)n * 1024 + h * 64;
    float acc = 0.f;
    #pragma unroll
    for (int e8 = 0; e8 < 8; e8++) {
      B8 v = *(const B8*)(wrow + e8 * 8);
      #pragma unroll
      for (int j = 0; j < 8; j++) acc += creg[e8 * 8 + j] * __bfloat162float(v.h[j]);
    }
    // fragment-major: col = h*64+lane -> q = h*8 + (lane>>3), e = lane&7
    W2T[(size_t)b * 1048576 +
        (((size_t)(n >> 4) * 128 + h * 8 + (lane >> 3)) * 16 + (n & 15)) * 8 + (lane & 7)]
        = __float2bfloat16(acc);
  }
}

// ---------------- out[b] = Yq[b] @ W2T[b]^T + blin, fp32 output -------------------
// per batch: M=4096, N=1024, K=1024; fragment-major operands; grid 512
// XCD-chunked swizzle: each XCD owns one batch (64 blocks): W2T[b] (2MB) L2-resident.
__global__ __launch_bounds__(512, 2)
void gemm_out(const bf16* __restrict__ Aall, const bf16* __restrict__ BTall,
              float* __restrict__ Call, const float* __restrict__ bias)
{
  __shared__ __align__(16) struct { bf16 a[4 * 8192]; bf16 b[4 * 8192]; } sm;
  const int t = threadIdx.x;
  const int wave = t >> 6, lane = t & 63;
  const int lr = lane & 15, kq = lane >> 4;
  const int wm = wave >> 2, wn = wave & 3;
  // bijective XCD swizzle: 512 = 8 * 64; XCD x -> batch x
  const int bid = (int)blockIdx.x;
  const int swz = (bid & 7) * 64 + (bid >> 3);
  const int bz = swz >> 6;
  const int r  = swz & 63;
  const int bm = r >> 2, bn = r & 3;
  const int m0 = bm * 256, n0 = bn * 256;
  const bf16* A  = Aall  + (size_t)bz * 4194304;
  const bf16* BT = BTall + (size_t)bz * 1048576;
  float* C       = Call  + (size_t)bz * 4194304;

  const bf16* aop0 = A + (size_t)((m0 >> 4) + wave) * 16384 + lane * 8;
  const bf16* aop1 = aop0 + 131072;
  const bf16* bop0 = BT + (size_t)((n0 >> 4) + wave) * 16384 + lane * 8;
  const bf16* bop1 = bop0 + 131072;
  const int wd0 = wave * 512;
  const int wd1 = 4096 + wave * 512;

  const int aoff = wm * 4096 + lane * 8;
  const int boff = wn * 2048 + lane * 8;

  const f32x4 zero = {0.f, 0.f, 0.f, 0.f};
  f32x4 acc[8][4];
  #pragma unroll
  for (int i = 0; i < 8; i++)
    #pragma unroll
    for (int j = 0; j < 4; j++) acc[i][j] = zero;

  gemm_mainloop_256(aop0, aop1, bop0, bop1, sm.a, sm.b, wd0, wd1,
                    aoff, boff, acc);

  float bv[4];
  #pragma unroll
  for (int j = 0; j < 4; j++) bv[j] = bias[n0 + wn * 64 + j * 16 + lr];
  #pragma unroll
  for (int i = 0; i < 8; i++) {
    const int row0 = m0 + wm * 128 + i * 16 + kq * 4;
    #pragma unroll
    for (int j = 0; j < 4; j++) {
      const int col = n0 + wn * 64 + j * 16 + lr;
      const float bvj = bv[j];
      #pragma unroll
      for (int r2 = 0; r2 < 4; r2++)
        C[(size_t)(row0 + r2) * 1024 + col] = acc[i][j][r2] + bvj;
    }
  }
}

// ---------------------------------------------------------------------------------
extern "C" void kernel_launch(void* const* d_in, const int* in_sizes, int n_in,
                              void* d_out, int out_size, void* d_ws, size_t ws_size,
                              hipStream_t stream) {
  (void)in_sizes; (void)n_in; (void)out_size; (void)ws_size;
  const float* x    = (const float*)d_in[0];
  const float* Wq   = (const float*)d_in[1];
  const float* Wkv  = (const float*)d_in[2];
  const float* Wlin = (const float*)d_in[3];
  const float* blin = (const float*)d_in[4];
  float* out = (float*)d_out;              // reference output dtype = float32

  // workspace layout (~160 MB total); all staged operands fragment-major
  bf16* x_bf  = (bf16*)d_ws;                  // 33,554,432
  bf16* WTc   = x_bf + 33554432;              // 3,145,728   [Wq^T | Wkv^T] frag-major
  bf16* WlinT = WTc + 3145728;                // 1,048,576   row-major (make_w2t)
  bf16* Yq    = WlinT + 1048576;              // 33,554,432  frag-major
  bf16* W2T   = Yq + 33554432;                // 8,388,608   frag-major
  float* ctxAcc = (float*)(W2T + 8388608);    // 128 * 4160 fp32 (R | Z)

  cast_x_frag<<<2048, 256, 0, stream>>>(x, x_bf);
  wcast_frag<<<dim3(4, 64), 256, 0, stream>>>(Wq, WTc, 1024, 0);
  wcast_frag<<<dim3(4, 128), 256, 0, stream>>>(Wkv, WTc, 2048, 1024);
  tcast<<<dim3(32, 32), dim3(32, 8), 0, stream>>>(Wlin, WlinT, 1024, 1024);

  hipMemsetAsync(ctxAcc, 0, (size_t)128 * 4160 * sizeof(float), stream);

  gemm_qkv<<<dim3(128 * QKV_NT), 512, 0, stream>>>(x_bf, WTc, Yq, ctxAcc);
  make_w2t<<<dim3(16, 128), 256, 0, stream>>>(ctxAcc, WlinT, W2T);
  gemm_out<<<dim3(512), 512, 0, stream>>>(Yq, W2T, out, blin);
}